// Round 9
// baseline (301.096 us; speedup 1.0000x reference)
//
#include <hip/hip_runtime.h>

typedef unsigned int u32;
typedef unsigned short u16;

#define NT 128
#define NBLK 2500

typedef __attribute__((ext_vector_type(8))) short bh8;
typedef __attribute__((ext_vector_type(4))) float f4;
union U8 { uint4 u; bh8 h; };

__device__ __forceinline__ u16 fb(float x){            // fp32->bf16 RNE
    u32 u = __float_as_uint(x);
    u += 0x7fffu + ((u>>16)&1u);
    return (u16)(u>>16);
}
__device__ __forceinline__ u32 pk2(float a, float b){
    return (u32)fb(a) | ((u32)fb(b)<<16);
}
__device__ __forceinline__ float bf_lo(u32 w){ return __uint_as_float(w<<16); }
__device__ __forceinline__ float bf_hi(u32 w){ return __uint_as_float(w & 0xffff0000u); }

// gelu via A&S 7.1.26 erf (|err|<=1.5e-7), branchless
__device__ __forceinline__ float gelu(float x){
    float z = fabsf(x) * 0.70710678118654752f;
    float t = 1.0f / (1.0f + 0.3275911f * z);
    float e = __expf(-z*z);
    float poly = t*(0.254829592f + t*(-0.284496736f + t*(1.421413741f +
                 t*(-1.453152027f + t*1.061405429f))));
    float erfz = 1.0f - poly*e;                       // erf(|z|) >= 0
    u32 s = (__float_as_uint(erfz) & 0x7fffffffu) | (__float_as_uint(x) & 0x80000000u);
    return 0.5f*x*(1.0f + __uint_as_float(s));
}

// ---------- prep: pack W1^T / W2^T (k and v) into MFMA A-frag order, bf16 ----
// ws16 layout (u16): [A1K:2048][A1V:2048][A2K:16384][A2V:16384]
__global__ void prep_pack(const float* __restrict__ kw1, const float* __restrict__ vw1,
                          const float* __restrict__ kw2, const float* __restrict__ vw2,
                          u16* __restrict__ ws16)
{
    int t = blockIdx.x*256 + threadIdx.x;        // 0..36863
    if (t >= 36864) return;
    float val;
    if (t < 4096){
        const float* w1 = (t < 2048) ? kw1 : vw1;
        int u = t & 2047;
        int mt = u >> 9, lane = (u>>3)&63, j = u&7;
        int m = mt*16 + (lane&15);
        int x = (lane>>4)*8 + j;
        val = w1[x*64 + m];
    } else {
        int s2 = t - 4096;
        const float* w2 = (s2 < 16384) ? kw2 : vw2;
        int u = s2 & 16383;
        int blkidx = u >> 9;                      // mt*2+s
        int mt = blkidx >> 1, s = blkidx & 1;
        int lane = (u>>3)&63, j = u&7;
        int ij = mt*16 + (lane&15);
        int c  = s*32 + (lane>>4)*8 + j;
        val = w2[c*256 + ij];
    }
    ws16[t] = fb(val);
}

// ---------- one radial conv via MFMA: t2[16] stays in registers ------------
// HARD CONSTRAINTS (each verified by a failing round):
//  * mt loop fully unrolled — partial unroll (r5) => WRONG results.
//  * REAL `s_waitcnt lgkmcnt(0)` between H-tile ds_writes and b2f ds_reads —
//    the exchange is CROSS-LANE within the wave. Compiler-only fence (r7) =>
//    WRONG results.
//  * NO register-cap attributes (waves_per_eu/launch_bounds min-waves) — both
//    caps tried (r4: 305MB spill; r7/r8: absmax ~1e-2 corruption, same family
//    as r5's masked-scratch bug). Occupancy comes from LDS only.
// NEW (r9): per-nt H-tile regions -> write-all / ONE drain / read-all / drain
// (r6 did the drain pair per nt: 8 serialization points per conv -> now 2).
__device__ __forceinline__ void conv_mfma(
    const u16* __restrict__ pA1, const u16* __restrict__ pA2,
    const float* __restrict__ b1g, const float* __restrict__ b2g,
    const bh8* __restrict__ B1f,          // [4] cached ef frags
    const u32* __restrict__ tmpS,         // stride 10 u32 rows (16 bf16)
    u16* __restrict__ hT,                 // wave base: 4 regions x 1152 u16
    float* __restrict__ t2v,              // [16] regs out
    int w, int lane)
{
    const int r = lane & 15, q = lane >> 4;
    bh8 b2f0[4], b2f1[4];
    float tm[4][4];

    // ---- staging loop1: all MFMA1 -> gelu -> H-tile writes (no reads) ----
    #pragma unroll
    for (int nt=0; nt<4; ++nt){
        u16* hTn = hT + nt*1152;
        #pragma unroll
        for (int mt=0; mt<4; ++mt){
            bh8 a1 = *(const bh8*)(pA1 + ((mt*64 + lane)<<3));
            f4 d1 = {0.f,0.f,0.f,0.f};
            d1 = __builtin_amdgcn_mfma_f32_16x16x32_bf16(a1, B1f[nt], d1, 0,0,0);
            float4 bv = *(const float4*)(b1g + mt*16 + q*4);
            float g0 = gelu(d1[0]+bv.x), g1 = gelu(d1[1]+bv.y);
            float g2 = gelu(d1[2]+bv.z), g3 = gelu(d1[3]+bv.w);
            uint2 pk; pk.x = pk2(g0,g1); pk.y = pk2(g2,g3);
            *(uint2*)(hTn + r*72 + mt*16 + q*4) = pk;
        }
    }
    __asm__ volatile("s_waitcnt lgkmcnt(0)" ::: "memory");
    // ---- staging loop2: all B2-frag + tmp reads ----
    #pragma unroll
    for (int nt=0; nt<4; ++nt){
        const u16* hTn = hT + nt*1152;
        b2f0[nt] = *(const bh8*)(hTn + r*72 +      q*8);   // chans q*8..+7
        b2f1[nt] = *(const bh8*)(hTn + r*72 + 32 + q*8);   // chans 32+q*8..+7
        uint2 tp = *(const uint2*)(tmpS + ((w*4+nt)*16 + r)*10 + q*2);
        tm[nt][0]=bf_lo(tp.x); tm[nt][1]=bf_hi(tp.x);
        tm[nt][2]=bf_lo(tp.y); tm[nt][3]=bf_hi(tp.y);
    }
    // drain: reads complete before caller (V conv) rewrites hT (WAR safety)
    __asm__ volatile("s_waitcnt lgkmcnt(0)" ::: "memory");

    // ---- main: RW^T tiles (M=ij, N=edges) + fused tmp contraction ----------
    #pragma unroll
    for (int mt=0; mt<16; ++mt){
        bh8 a2s0 = *(const bh8*)(pA2 + (((mt*2+0)*64 + lane)<<3));
        bh8 a2s1 = *(const bh8*)(pA2 + (((mt*2+1)*64 + lane)<<3));
        float4 bv = *(const float4*)(b2g + mt*16 + q*4);
        #pragma unroll
        for (int nt=0; nt<4; ++nt){
            f4 acc = {0.f,0.f,0.f,0.f};
            acc = __builtin_amdgcn_mfma_f32_16x16x32_bf16(a2s0, b2f0[nt], acc, 0,0,0);
            acc = __builtin_amdgcn_mfma_f32_16x16x32_bf16(a2s1, b2f1[nt], acc, 0,0,0);
            float p = (acc[0]+bv.x)*tm[nt][0] + (acc[1]+bv.y)*tm[nt][1]
                    + (acc[2]+bv.z)*tm[nt][2] + (acc[3]+bv.w)*tm[nt][3];
            p += __shfl_xor(p, 16);
            p += __shfl_xor(p, 32);
            if (q == nt) t2v[mt] = p;   // owner lane of edge nt*16+r is (q=nt,r)
        }
    }
}

// ---------------- fused main kernel -------------------------------------------
// launch_bounds(NT,1): NO register cap (see constraints above). VGPR ~220 ->
// 2 waves/SIMD; LDS 36864B -> 4 blocks/CU -> 8 waves/CU (same as r6) with
// 4x fewer staging drains.
__global__ __launch_bounds__(NT, 1) void eqattn_main(
    const float* __restrict__ bk1, const float* __restrict__ bk2,
    const float* __restrict__ bv1, const float* __restrict__ bv2,
    const float* __restrict__ efg, const float* __restrict__ fg,
    const float* __restrict__ qw,  const float* __restrict__ qb,
    const float* __restrict__ kb1, const float* __restrict__ kb2,
    const float* __restrict__ vb1, const float* __restrict__ vb2,
    const float* __restrict__ ow,  const float* __restrict__ ob,
    const int* __restrict__ nidx,  const u16* __restrict__ ws16,
    float* __restrict__ outg)
{
    __shared__ __align__(16) u32 sTmpK[1280];  // 5120B: tmp-k bf16 rows (stride 10) -> attn scratch
    __shared__ __align__(16) u32 sTmpV[1280];  // 5120B: tmp-v bf16 rows
    __shared__ __align__(16) u32 sKS [2048];   // 8192B: k rows 16 u32 (pair-swizzled)
    __shared__ __align__(16) u32 sU  [4608];   // 18432B: H tiles (2 waves x 4 nt x 1152 u16) -> V rows
    // total 36864B -> 4 blocks/CU

    const int t    = threadIdx.x;
    const int lane = t & 63;
    const int w    = t >> 6;
    const int r    = lane & 15, q = lane >> 4;
    const int n0   = blockIdx.x * 8;
    const int e    = blockIdx.x * 128 + t;

    const u16* pA1k = ws16;
    const u16* pA1v = ws16 + 2048;
    const u16* pA2k = ws16 + 4096;
    const u16* pA2v = ws16 + 20480;

    // ---- phase 0: gather f[src], tmpk/tmpv (bf16 rows) ----
    {
        int src = nidx[e];
        const float4* fr = (const float4*)(fg + src*32);
        float fs[32];
        #pragma unroll
        for (int i=0;i<8;++i){
            float4 v = fr[i];
            fs[i*4]=v.x; fs[i*4+1]=v.y; fs[i*4+2]=v.z; fs[i*4+3]=v.w;
        }
        float4 ka = *(const float4*)(bk1+e*8), kbv = *(const float4*)(bk1+e*8+4);
        float4 va = *(const float4*)(bv1+e*8), vbv = *(const float4*)(bv1+e*8+4);
        float b1k[8] = {ka.x,ka.y,ka.z,ka.w,kbv.x,kbv.y,kbv.z,kbv.w};
        float b1v[8] = {va.x,va.y,va.z,va.w,vbv.x,vbv.y,vbv.z,vbv.w};
        float tk[16], tv[16];
        #pragma unroll
        for (int m=0;m<8;++m){
            float t0=0.f,t1=0.f,u0=0.f,u1=0.f;
            #pragma unroll
            for (int d=0;d<4;++d){
                float fv = fs[m*4+d];
                t0 += fv*b1k[d*2];  t1 += fv*b1k[d*2+1];
                u0 += fv*b1v[d*2];  u1 += fv*b1v[d*2+1];
            }
            tk[m*2]=t0; tk[m*2+1]=t1; tv[m*2]=u0; tv[m*2+1]=u1;
        }
        #pragma unroll
        for (int i=0;i<8;++i){
            sTmpK[t*10+i] = pk2(tk[i*2], tk[i*2+1]);
            sTmpV[t*10+i] = pk2(tv[i*2], tv[i*2+1]);
        }
    }

    // ---- B1 frags: ef rows -> bf16 (shared by K and V convs) ----
    bh8 B1f[4];
    #pragma unroll
    for (int nt=0; nt<4; ++nt){
        int eg = blockIdx.x*128 + (w*4+nt)*16 + r;
        float4 ea = *(const float4*)(efg + eg*32 + q*8);
        float4 eb = *(const float4*)(efg + eg*32 + q*8 + 4);
        U8 uu;
        uu.u.x = pk2(ea.x, ea.y); uu.u.y = pk2(ea.z, ea.w);
        uu.u.z = pk2(eb.x, eb.y); uu.u.w = pk2(eb.z, eb.w);
        B1f[nt] = uu.h;
    }
    __asm__ volatile("s_waitcnt lgkmcnt(0)" ::: "memory");

    u16* hT = (u16*)sU + w*4608;

    // ---- K conv ----
    float t2k[16];
    conv_mfma(pA1k, pA2k, kb1, kb2, B1f, sTmpK, hT, t2k, w, lane);
    {
        float4 c0 = *(const float4*)(bk2 + e*8);
        float4 c1 = *(const float4*)(bk2 + e*8 + 4);
        #pragma unroll
        for (int m=0;m<8;++m){
            float t20 = t2k[2*m], t21 = t2k[2*m+1];
            uint2 pk;
            pk.x = pk2(t20*c0.x + t21*c1.x, t20*c0.y + t21*c1.y);
            pk.y = pk2(t20*c0.z + t21*c1.z, t20*c0.w + t21*c1.w);
            *(uint2*)(sKS + t*16 + ((m ^ (t&7))<<1)) = pk;
        }
    }
    // ---- V conv ----
    float t2va[16];
    conv_mfma(pA1v, pA2v, vb1, vb2, B1f, sTmpV, hT, t2va, w, lane);
    __syncthreads();   // all waves done with hT (sU) before V rows overlay it
    u32* sVS = sU;
    {
        float4 c0 = *(const float4*)(bv2 + e*8);
        float4 c1 = *(const float4*)(bv2 + e*8 + 4);
        #pragma unroll
        for (int m=0;m<8;++m){
            float t20 = t2va[2*m], t21 = t2va[2*m+1];
            uint2 pk;
            pk.x = pk2(t20*c0.x + t21*c1.x, t20*c0.y + t21*c1.y);
            pk.y = pk2(t20*c0.z + t21*c1.z, t20*c0.w + t21*c1.w);
            *(uint2*)(sVS + t*16 + ((m ^ (t&7))<<1)) = pk;
        }
    }
    __syncthreads();    // all k/v rows visible; tmp regions now reusable

    float* qS  = (float*)sTmpK;        // [8][33] = 264 floats
    float* lg  = (float*)sTmpK + 264;  // [32][17] = 544 floats
    float* aoS = (float*)sTmpK + 808;  // [8][33] = 264 floats

    // ---- q = eq_linear(f, q_w, q_b): 256 tasks ----
    #pragma unroll 1
    for (int p=0;p<2;++p){
        int task = p*NT + t;
        int ln = task>>5, m=(task>>2)&7, d=task&3;
        const float* frow = fg + (n0+ln)*32;
        int rr = ((d>0)?8:0) + m;
        float acc = (d==0) ? qb[m] : 0.f;
        #pragma unroll
        for (int mm=0;mm<8;++mm) acc += qw[rr*8+mm]*frow[mm*4+d];
        qS[ln*33 + m*4 + d] = acc;
    }
    __syncthreads();

    // ---- logits: 512 tasks ----
    #pragma unroll 1
    for (int p=0;p<4;++p){
        int task = p*NT + t;
        int ln = task>>6, hh=(task>>4)&3, k=task&15;
        int row = ln*16 + k;
        const float* qr = qS + ln*33 + hh*8;
        uint2 k0 = *(const uint2*)(sKS + row*16 + (((hh<<1)     ^ (row&7))<<1));
        uint2 k1 = *(const uint2*)(sKS + row*16 + ((((hh<<1)|1) ^ (row&7))<<1));
        float acc = qr[0]*bf_lo(k0.x)+qr[1]*bf_hi(k0.x)
                  + qr[2]*bf_lo(k0.y)+qr[3]*bf_hi(k0.y)
                  + qr[4]*bf_lo(k1.x)+qr[5]*bf_hi(k1.x)
                  + qr[6]*bf_lo(k1.y)+qr[7]*bf_hi(k1.y);
        lg[(ln*4+hh)*17 + k] = acc * 0.35355339059327373f;
    }
    __syncthreads();

    // ---- softmax over 16 neighbors: 32 rows ----
    if (t < 32){
        float* row = lg + t*17;
        float mx = row[0];
        #pragma unroll
        for (int k=1;k<16;++k) mx = fmaxf(mx, row[k]);
        float ev[16]; float s=0.f;
        #pragma unroll
        for (int k=0;k<16;++k){ ev[k] = __expf(row[k]-mx); s += ev[k]; }
        float inv = 1.f/s;
        #pragma unroll
        for (int k=0;k<16;++k) row[k] = ev[k]*inv;
    }
    __syncthreads();

    // ---- attention output: 256 tasks ----
    #pragma unroll 1
    for (int p=0;p<2;++p){
        int task = p*NT + t;
        int ln = task>>5, comp = task&31, hh = comp>>3;
        const float* ar = lg + (ln*4+hh)*17;
        float acc=0.f;
        #pragma unroll
        for (int k=0;k<16;++k){
            int row = ln*16 + k;
            u32 wv = sVS[row*16 + (((comp>>2) ^ (row&7))<<1) + ((comp>>1)&1)];
            acc += ar[k] * ((comp&1) ? bf_hi(wv) : bf_lo(wv));
        }
        aoS[ln*33 + comp] = acc;
    }
    __syncthreads();

    // ---- final eq_linear(o_w, o_b) -> fp32 out ----
    #pragma unroll 1
    for (int p=0;p<2;++p){
        int task = p*NT + t;
        int ln = task>>5, m=(task>>2)&7, d=task&3;
        int rr = ((d>0)?8:0) + m;
        float acc = (d==0) ? ob[m] : 0.f;
        #pragma unroll
        for (int mm=0;mm<8;++mm) acc += ow[rr*8+mm]*aoS[ln*33 + mm*4 + d];
        outg[(n0+ln)*32 + m*4 + d] = acc;
    }
}

extern "C" void kernel_launch(void* const* d_in, const int* in_sizes, int n_in,
                              void* d_out, int out_size, void* d_ws, size_t ws_size,
                              hipStream_t stream)
{
    (void)in_sizes; (void)n_in; (void)out_size; (void)ws_size;
    const float* bk1 = (const float*)d_in[0];
    const float* bk2 = (const float*)d_in[1];
    const float* bv1 = (const float*)d_in[2];
    const float* bv2 = (const float*)d_in[3];
    const float* efg = (const float*)d_in[4];
    const float* fg  = (const float*)d_in[5];
    const float* qw  = (const float*)d_in[6];
    const float* qb  = (const float*)d_in[7];
    const float* kw1 = (const float*)d_in[8];
    const float* kb1 = (const float*)d_in[9];
    const float* kw2 = (const float*)d_in[10];
    const float* kb2 = (const float*)d_in[11];
    const float* vw1 = (const float*)d_in[12];
    const float* vb1 = (const float*)d_in[13];
    const float* vw2 = (const float*)d_in[14];
    const float* vb2 = (const float*)d_in[15];
    const float* ow  = (const float*)d_in[16];
    const float* ob  = (const float*)d_in[17];
    const int* nidx  = (const int*)d_in[18];
    u16* ws16 = (u16*)d_ws;

    prep_pack<<<144, 256, 0, stream>>>(kw1, vw1, kw2, vw2, ws16);
    eqattn_main<<<NBLK, NT, 0, stream>>>(
        bk1,bk2,bv1,bv2, efg, fg, qw,qb, kb1,kb2, vb1,vb2,
        ow,ob, nidx, ws16, (float*)d_out);
}